// Round 2
// baseline (916.357 us; speedup 1.0000x reference)
//
#include <hip/hip_runtime.h>
#include <hip/hip_bf16.h>

// Problem constants (from reference)
#define NNODE 25000
#define PEDGE 400000
#define FDIM  224      // F = TF = 224; q/k: 7 heads x 32, v: 4 heads x 56
#define NORD  15
#define NXOUT (NNODE*FDIM)
#define NTILE 3125     // PEDGE/128

typedef __bf16 bf16x8 __attribute__((ext_vector_type(8)));
typedef __bf16 bf16x4 __attribute__((ext_vector_type(4)));
typedef short  s16x8  __attribute__((ext_vector_type(8)));
typedef float  f32x4  __attribute__((ext_vector_type(4)));

// MFMA wrapper: tolerate either v8bf16 or v8i16 builtin signature across ROCm versions.
template <typename V>
__device__ __forceinline__ auto mfma_impl(V a, V b, f32x4 c, int)
    -> decltype(__builtin_amdgcn_mfma_f32_16x16x32_bf16(a, b, c, 0, 0, 0)) {
  return __builtin_amdgcn_mfma_f32_16x16x32_bf16(a, b, c, 0, 0, 0);
}
template <typename V>
__device__ __forceinline__ f32x4 mfma_impl(V a, V b, f32x4 c, long) {
  return __builtin_amdgcn_mfma_f32_16x16x32_bf16(
      __builtin_bit_cast(s16x8, a), __builtin_bit_cast(s16x8, b), c, 0, 0, 0);
}
__device__ __forceinline__ f32x4 MFMA_BF16(bf16x8 a, bf16x8 b, f32x4 c) {
  return mfma_impl(a, b, c, 0);
}

__device__ __forceinline__ float siluf(float x) { return x / (1.0f + __expf(-x)); }
__device__ __forceinline__ unsigned short f2bf(float x) {
  __hip_bfloat16 h = __float2bfloat16(x);
  return __builtin_bit_cast(unsigned short, h);
}
__device__ __forceinline__ float bf2f(unsigned short u) {
  unsigned int v = ((unsigned int)u) << 16;
  return __builtin_bit_cast(float, v);
}

// ---------------------------------------------------------------------------
// k_pre: (a) node q,k,v projections, 32 nodes/block, weights in registers;
//        (b) CSR row_start from sorted idx_i;
//        (c) W1cat (64x224, block-diag + bias row 35) -> swizzled bf16.
// ---------------------------------------------------------------------------
#define NPB 32
#define NBNODE 782   // ceil(25000/32)
__global__ __launch_bounds__(256) void k_pre(
    const float* __restrict__ x, const float* __restrict__ Wq,
    const float* __restrict__ Wk, const float* __restrict__ Wv,
    const int* __restrict__ idx_i,
    const float* __restrict__ W1r, const float* __restrict__ W1s,
    const float* __restrict__ b1r, const float* __restrict__ b1s,
    unsigned short* __restrict__ q_ws, unsigned short* __restrict__ k_ws,
    unsigned short* __restrict__ v_ws, int* __restrict__ rs,
    unsigned short* __restrict__ W1sw) {
  int b = blockIdx.x, t = threadIdx.x;
  if (b < NBNODE) {
    __shared__ float xs[NPB * FDIM];           // 28,672 B
    int n0 = b * NPB;
    int ncnt = NNODE - n0; if (ncnt > NPB) ncnt = NPB;
    // stage x rows (coalesced float4)
    const float4* x4 = (const float4*)(x + n0 * FDIM);
    float4* xs4 = (float4*)xs;
    int tot4 = ncnt * (FDIM / 4);
    for (int i = t; i < tot4; i += 256) xs4[i] = x4[i];
    // per-thread weight rows in registers
    float wq[32], wk[32], wv[56];
    int h = 0, d = 0;
    if (t < FDIM) {
      #pragma unroll
      for (int j = 0; j < 32; j++) { wq[j] = Wq[t*32 + j]; wk[j] = Wk[t*32 + j]; }
      h = t / 56; d = t - h*56;
      #pragma unroll
      for (int j = 0; j < 56; j++) wv[j] = Wv[(h*56 + d)*56 + j];
    }
    __syncthreads();
    if (t < FDIM) {
      int qh = t >> 5;
      for (int m = 0; m < ncnt; m++) {
        const float* xr = xs + m*FDIM;
        const float* xh = xr + (qh << 5);
        float aq = 0.f, ak = 0.f;
        #pragma unroll
        for (int j = 0; j < 32; j++) { aq += wq[j]*xh[j]; ak += wk[j]*xh[j]; }
        int n = n0 + m;
        q_ws[n*FDIM + t] = f2bf(siluf(aq));
        k_ws[n*FDIM + t] = f2bf(siluf(ak));
        const float* xv = xr + h*56;
        float av = 0.f;
        #pragma unroll
        for (int j = 0; j < 56; j++) av += wv[j]*xv[j];
        v_ws[n*FDIM + t] = f2bf(av);   // no silu on v
      }
    }
  } else if (b < NBNODE + 1563) {
    int p = (b - NBNODE)*256 + t;
    if (p < PEDGE) {
      int cur = idx_i[p];
      if (p == 0) { for (int v = 0; v <= cur; v++) rs[v] = 0; }
      else { int prev = idx_i[p-1]; for (int v = prev+1; v <= cur; v++) rs[v] = p; }
      if (p == PEDGE-1) { for (int v = cur+1; v <= NNODE; v++) rs[v] = PEDGE; }
    }
  } else {
    // W1cat[row<64][col<224]; row 35 = b1cat (bias folded into GEMM)
    for (int lin = t; lin < 64*224; lin += 256) {
      int row = lin / 224, col = lin - row*224;
      float v = 0.f;
      if (row < 32) { if (col < 112) v = W1r[row*112 + col]; }
      else if (row < 35) { if (col >= 112) v = W1s[(row-32)*112 + (col-112)]; }
      else if (row == 35) v = (col < 112) ? b1r[col] : b1s[col-112];
      int nt = col >> 4, lanelo = col & 15, k = row >> 5, hi = (row >> 3) & 3, j = row & 7;
      W1sw[(((nt*2 + k)*64) + hi*16 + lanelo)*8 + j] = f2bf(v);
    }
  }
}

// ---------------------------------------------------------------------------
// k_edge: fused edge MLP + alpha. 512-thread blocks (8 waves x 16 edges),
// 1 block/CU -> 2 waves/SIMD. Swapped MFMA operands: D[feature][edge], so
// epilogue q/k gathers are 8B vector loads and biases fold into the GEMMs.
// No barriers in the tile loop (per-wave-private h1 rows).
// ---------------------------------------------------------------------------
__global__ __launch_bounds__(512) void k_edge(
    const float* __restrict__ rbf, const float* __restrict__ cut,
    const float* __restrict__ ev,
    const int* __restrict__ idx_i, const int* __restrict__ idx_j,
    const unsigned short* __restrict__ W1sw,
    const float* __restrict__ W2r, const float* __restrict__ W2s,
    const float* __restrict__ b2r, const float* __restrict__ b2s,
    const unsigned short* __restrict__ q_ws, const unsigned short* __restrict__ k_ws,
    float* __restrict__ alpha_ws) {
  __shared__ __bf16 W2sw[224*224];   // 100,352 B swizzled (B/A-frag order)
  __shared__ __bf16 h1s[128*232];    // 59,392 B: 8 waves x 16 rows, +8 pad
  __shared__ float b2c[224];         // 896 B
  int tid = threadIdx.x;
  for (int lin = tid; lin < 224*224; lin += 512) {
    float v = (lin < 112*224) ? W2r[lin] : W2s[lin - 112*224];  // W2cat = [W2r; W2s]
    int row = lin / 224, col = lin - row*224;
    int nt = col >> 4, lanelo = col & 15, k = row >> 5, hi = (row >> 3) & 3, j = row & 7;
    W2sw[(((nt*7 + k)*64) + hi*16 + lanelo)*8 + j] = (__bf16)v;
  }
  if (tid < FDIM) b2c[tid] = b2r[tid] + b2s[tid];
  __syncthreads();
  int wave = tid >> 6, lane = tid & 63;
  int mrow = lane & 15, quad = lane >> 4;
  int lrow = (wave*16 + mrow)*232;   // this lane's h1 row base (edge = mrow)
  for (int T = blockIdx.x; T < NTILE; T += gridDim.x) {
    int base = T*128 + wave*16;
    int e = base + mrow;             // this lane's edge
    float cu = cut[e];
    int ie = idx_i[e], je = idx_j[e];
    // ---- u fragment (B-operand): u[e][k] = [rbf*cut | l0 | 1 | 0...] ----
    bf16x8 u0, u1;
    const float4* r4 = (const float4*)(rbf + e*32 + quad*8);
    float4 v0 = r4[0], v1 = r4[1];
    u0[0] = (__bf16)(v0.x*cu); u0[1] = (__bf16)(v0.y*cu);
    u0[2] = (__bf16)(v0.z*cu); u0[3] = (__bf16)(v0.w*cu);
    u0[4] = (__bf16)(v1.x*cu); u0[5] = (__bf16)(v1.y*cu);
    u0[6] = (__bf16)(v1.z*cu); u0[7] = (__bf16)(v1.w*cu);
    #pragma unroll
    for (int j = 0; j < 8; j++) u1[j] = (__bf16)0.f;
    if (quad == 0) {
      const float* evi = ev + ie*NORD; const float* evj = ev + je*NORD;
      float s0 = 0.f, s1 = 0.f, s2 = 0.f;
      #pragma unroll
      for (int o = 0; o < 3; o++)  { float d = evj[o]-evi[o]; s0 += d*d; }
      #pragma unroll
      for (int o = 3; o < 8; o++)  { float d = evj[o]-evi[o]; s1 += d*d; }
      #pragma unroll
      for (int o = 8; o < 15; o++) { float d = evj[o]-evi[o]; s2 += d*d; }
      u1[0] = (__bf16)s0; u1[1] = (__bf16)s1; u1[2] = (__bf16)s2;
      u1[3] = (__bf16)1.0f;   // bias row k=35
    }
    // ---- layer 1: D[f][e]; lane holds f = nt*16+quad*4+r for edge mrow ----
    #pragma unroll
    for (int nt = 0; nt < 14; nt++) {
      bf16x8 b0 = *(const bf16x8*)(W1sw + ((nt*2 + 0)*64 + lane)*8);
      bf16x8 b1 = *(const bf16x8*)(W1sw + ((nt*2 + 1)*64 + lane)*8);
      f32x4 acc = {0.f, 0.f, 0.f, 0.f};
      acc = MFMA_BF16(b0, u0, acc);
      acc = MFMA_BF16(b1, u1, acc);
      bf16x4 pk;
      #pragma unroll
      for (int r = 0; r < 4; r++) pk[r] = (__bf16)siluf(acc[r]);
      *(bf16x4*)&h1s[lrow + nt*16 + quad*4] = pk;   // 8B ds_write_b64
    }
    // ---- h1 B-fragments (same-wave RAW through LDS) ----
    bf16x8 hb[7];
    #pragma unroll
    for (int kt = 0; kt < 7; kt++)
      hb[kt] = *(const bf16x8*)&h1s[lrow + kt*32 + quad*8];
    // ---- layer 2 + alpha epilogue ----
    #pragma unroll
    for (int h = 0; h < 7; h++) {
      float part = 0.f;
      #pragma unroll
      for (int t2 = 0; t2 < 2; t2++) {
        int nt = h*2 + t2;
        float4 bc = *(const float4*)&b2c[nt*16 + quad*4];
        f32x4 acc = {bc.x, bc.y, bc.z, bc.w};   // bias as C-init
        #pragma unroll
        for (int kt = 0; kt < 7; kt++) {
          bf16x8 bb = *(const bf16x8*)&W2sw[((nt*7 + kt)*64 + lane)*8];
          acc = MFMA_BF16(bb, hb[kt], acc);
        }
        ushort4 q4 = *(const ushort4*)(q_ws + ie*FDIM + nt*16 + quad*4);
        ushort4 k4 = *(const ushort4*)(k_ws + je*FDIM + nt*16 + quad*4);
        part += acc[0]*bf2f(q4.x)*bf2f(k4.x);
        part += acc[1]*bf2f(q4.y)*bf2f(k4.y);
        part += acc[2]*bf2f(q4.z)*bf2f(k4.z);
        part += acc[3]*bf2f(q4.w)*bf2f(k4.w);
      }
      part += __shfl_xor(part, 16);
      part += __shfl_xor(part, 32);
      if (quad == 0) alpha_ws[e*7 + h] = part * cu;
    }
  }
}

// ---------------------------------------------------------------------------
// k_agg: one wave per node; 4-wide v loads; zeros for empty segments.
// ---------------------------------------------------------------------------
__global__ __launch_bounds__(256) void k_agg(
    const float* __restrict__ alpha_ws, const unsigned short* __restrict__ v_ws,
    const float* __restrict__ ylm, const int* __restrict__ idx_j,
    const int* __restrict__ rs, float* __restrict__ out) {
  int n = blockIdx.x*4 + (threadIdx.x >> 6);
  if (n >= NNODE) return;
  int lane = threadIdx.x & 63;
  int s = rs[n], e = rs[n+1];
  if (lane < 56) {
    int c = lane*4, h = lane/14;      // 4 cols per lane, same head (56%4==0)
    float ax = 0.f, ay = 0.f, az = 0.f, aw = 0.f;
    for (int p = s; p < e; p++) {
      int jj = idx_j[p];
      float a = alpha_ws[p*7 + h];
      ushort4 v4 = *(const ushort4*)(v_ws + jj*FDIM + c);
      ax += a*bf2f(v4.x); ay += a*bf2f(v4.y);
      az += a*bf2f(v4.z); aw += a*bf2f(v4.w);
    }
    float4 o4 = {ax, ay, az, aw};
    *(float4*)(out + n*FDIM + c) = o4;
  } else {
    int o = lane - 56;                // 0..7 ; second col o+8 (8..14)
    int dg0 = (o < 3) ? 0 : ((o < 8) ? 1 : 2);
    float a0 = 0.f, a1 = 0.f;
    for (int p = s; p < e; p++) {
      const float* ap = alpha_ws + p*7 + 4;
      a0 += ap[dg0] * ylm[p*NORD + o];
      if (o < 7) a1 += ap[2] * ylm[p*NORD + o + 8];
    }
    out[NXOUT + n*NORD + o] = a0;
    if (o < 7) out[NXOUT + n*NORD + o + 8] = a1;
  }
}

extern "C" void kernel_launch(void* const* d_in, const int* in_sizes, int n_in,
                              void* d_out, int out_size, void* d_ws, size_t ws_size,
                              hipStream_t stream) {
  const float* x     = (const float*)d_in[0];
  const float* ev    = (const float*)d_in[1];
  const float* rbf   = (const float*)d_in[2];
  const float* ylm   = (const float*)d_in[3];
  const float* cut   = (const float*)d_in[4];
  const int*   idx_i = (const int*)d_in[5];
  const int*   idx_j = (const int*)d_in[6];
  const float* W1r   = (const float*)d_in[7];
  const float* b1r   = (const float*)d_in[8];
  const float* W2r   = (const float*)d_in[9];
  const float* b2r   = (const float*)d_in[10];
  const float* W1s   = (const float*)d_in[11];
  const float* b1s   = (const float*)d_in[12];
  const float* W2s   = (const float*)d_in[13];
  const float* b2s   = (const float*)d_in[14];
  const float* Wq    = (const float*)d_in[15];
  const float* Wk    = (const float*)d_in[16];
  const float* Wv    = (const float*)d_in[17];
  float* out = (float*)d_out;
  char* ws = (char*)d_ws;
  unsigned short* q_ws  = (unsigned short*)(ws + 0);          // 11.2 MB
  unsigned short* k_ws  = (unsigned short*)(ws + 11200000);   // 11.2 MB
  unsigned short* v_ws  = (unsigned short*)(ws + 22400000);   // 11.2 MB
  float* alpha_ws       = (float*)(ws + 33600000);            // 11.2 MB
  int* rs               = (int*)(ws + 44800000);              // 100,004 B
  unsigned short* W1sw  = (unsigned short*)(ws + 44900016);   // 28,672 B

  k_pre<<<dim3(NBNODE + 1563 + 1), dim3(256), 0, stream>>>(
      x, Wq, Wk, Wv, idx_i, W1r, W1s, b1r, b1s, q_ws, k_ws, v_ws, rs, W1sw);
  k_edge<<<dim3(256), dim3(512), 0, stream>>>(
      rbf, cut, ev, idx_i, idx_j, W1sw, W2r, W2s, b2r, b2s,
      q_ws, k_ws, alpha_ws);
  k_agg<<<dim3(6250), dim3(256), 0, stream>>>(
      alpha_ws, v_ws, ylm, idx_j, rs, out);
}

// Round 3
// 842.719 us; speedup vs baseline: 1.0874x; 1.0874x over previous
//
#include <hip/hip_runtime.h>
#include <hip/hip_bf16.h>

// Problem constants (from reference)
#define NNODE 25000
#define PEDGE 400000
#define FDIM  224      // F = TF = 224; q/k: 7 heads x 32, v: 4 heads x 56
#define NORD  15
#define NXOUT (NNODE*FDIM)
#define NTILE 3125     // PEDGE/128

typedef __bf16 bf16x8 __attribute__((ext_vector_type(8)));
typedef short  s16x8  __attribute__((ext_vector_type(8)));
typedef float  f32x4  __attribute__((ext_vector_type(4)));

// MFMA wrapper: tolerate either v8bf16 or v8i16 builtin signature across ROCm versions.
template <typename V>
__device__ __forceinline__ auto mfma_impl(V a, V b, f32x4 c, int)
    -> decltype(__builtin_amdgcn_mfma_f32_16x16x32_bf16(a, b, c, 0, 0, 0)) {
  return __builtin_amdgcn_mfma_f32_16x16x32_bf16(a, b, c, 0, 0, 0);
}
template <typename V>
__device__ __forceinline__ f32x4 mfma_impl(V a, V b, f32x4 c, long) {
  return __builtin_amdgcn_mfma_f32_16x16x32_bf16(
      __builtin_bit_cast(s16x8, a), __builtin_bit_cast(s16x8, b), c, 0, 0, 0);
}
__device__ __forceinline__ f32x4 MFMA_BF16(bf16x8 a, bf16x8 b, f32x4 c) {
  return mfma_impl(a, b, c, 0);
}

__device__ __forceinline__ float siluf(float x) { return x / (1.0f + __expf(-x)); }
__device__ __forceinline__ unsigned short f2bf(float x) {
  __hip_bfloat16 h = __float2bfloat16(x);
  return __builtin_bit_cast(unsigned short, h);
}
__device__ __forceinline__ float bf2f(unsigned short u) {
  unsigned int v = ((unsigned int)u) << 16;
  return __builtin_bit_cast(float, v);
}

// DPP 16-lane row sum on the VALU pipe (replaces ds_swizzle shuffles).
template <int CTRL>
__device__ __forceinline__ float dpp_radd(float v) {
  int s = __builtin_amdgcn_update_dpp(0, __builtin_bit_cast(int, v), CTRL, 0xf, 0xf, true);
  return v + __builtin_bit_cast(float, s);
}
__device__ __forceinline__ float row16_sum(float v) {
  v = dpp_radd<0xB1>(v);    // quad_perm [1,0,3,2]  (xor 1)
  v = dpp_radd<0x4E>(v);    // quad_perm [2,3,0,1]  (xor 2)
  v = dpp_radd<0x124>(v);   // row_ror:4
  v = dpp_radd<0x128>(v);   // row_ror:8
  return v;                 // all 16 lanes of the row hold the sum
}

// ---------------------------------------------------------------------------
// k_pre: (a) node q,k,v projections, 32 nodes/block, weights in registers;
//        (b) CSR row_start from sorted idx_i;
//        (c) W1cat (64x224 block-diag + bias row 35) -> swizzled bf16 (global)
//        (d) W2cat (224x224) -> swizzled bf16 (global)
// ---------------------------------------------------------------------------
#define NPB 32
#define NBNODE 782   // ceil(25000/32)
__global__ __launch_bounds__(256) void k_pre(
    const float* __restrict__ x, const float* __restrict__ Wq,
    const float* __restrict__ Wk, const float* __restrict__ Wv,
    const int* __restrict__ idx_i,
    const float* __restrict__ W1r, const float* __restrict__ W1s,
    const float* __restrict__ b1r, const float* __restrict__ b1s,
    const float* __restrict__ W2r, const float* __restrict__ W2s,
    unsigned short* __restrict__ q_ws, unsigned short* __restrict__ k_ws,
    unsigned short* __restrict__ v_ws, int* __restrict__ rs,
    unsigned short* __restrict__ W1sw, unsigned short* __restrict__ W2sw) {
  int b = blockIdx.x, t = threadIdx.x;
  if (b < NBNODE) {
    __shared__ float xs[NPB * FDIM];           // 28,672 B
    int n0 = b * NPB;
    int ncnt = NNODE - n0; if (ncnt > NPB) ncnt = NPB;
    const float4* x4 = (const float4*)(x + n0 * FDIM);
    float4* xs4 = (float4*)xs;
    int tot4 = ncnt * (FDIM / 4);
    for (int i = t; i < tot4; i += 256) xs4[i] = x4[i];
    float wq[32], wk[32], wv[56];
    int h = 0, d = 0;
    if (t < FDIM) {
      #pragma unroll
      for (int j = 0; j < 32; j++) { wq[j] = Wq[t*32 + j]; wk[j] = Wk[t*32 + j]; }
      h = t / 56; d = t - h*56;
      #pragma unroll
      for (int j = 0; j < 56; j++) wv[j] = Wv[(h*56 + d)*56 + j];
    }
    __syncthreads();
    if (t < FDIM) {
      int qh = t >> 5;
      for (int m = 0; m < ncnt; m++) {
        const float* xr = xs + m*FDIM;
        const float* xh = xr + (qh << 5);
        float aq = 0.f, ak = 0.f;
        #pragma unroll
        for (int j = 0; j < 32; j++) { aq += wq[j]*xh[j]; ak += wk[j]*xh[j]; }
        int n = n0 + m;
        q_ws[n*FDIM + t] = f2bf(siluf(aq));
        k_ws[n*FDIM + t] = f2bf(siluf(ak));
        const float* xv = xr + h*56;
        float av = 0.f;
        #pragma unroll
        for (int j = 0; j < 56; j++) av += wv[j]*xv[j];
        v_ws[n*FDIM + t] = f2bf(av);   // no silu on v
      }
    }
  } else if (b < NBNODE + 1563) {
    int p = (b - NBNODE)*256 + t;
    if (p < PEDGE) {
      int cur = idx_i[p];
      if (p == 0) { for (int v = 0; v <= cur; v++) rs[v] = 0; }
      else { int prev = idx_i[p-1]; for (int v = prev+1; v <= cur; v++) rs[v] = p; }
      if (p == PEDGE-1) { for (int v = cur+1; v <= NNODE; v++) rs[v] = PEDGE; }
    }
  } else if (b == NBNODE + 1563) {
    // W1cat[row<64][col<224]; row 35 = b1cat (bias folded into GEMM)
    for (int lin = t; lin < 64*224; lin += 256) {
      int row = lin / 224, col = lin - row*224;
      float v = 0.f;
      if (row < 32) { if (col < 112) v = W1r[row*112 + col]; }
      else if (row < 35) { if (col >= 112) v = W1s[(row-32)*112 + (col-112)]; }
      else if (row == 35) v = (col < 112) ? b1r[col] : b1s[col-112];
      int nt = col >> 4, lanelo = col & 15, k = row >> 5, hi = (row >> 3) & 3, j = row & 7;
      W1sw[(((nt*2 + k)*64) + hi*16 + lanelo)*8 + j] = f2bf(v);
    }
  } else {
    // W2cat (224x224) -> swizzled global, output-linear (coalesced writes)
    int half = b - (NBNODE + 1564);      // 0 or 1
    int o0 = half * 25088;
    for (int o = o0 + t; o < o0 + 25088; o += 256) {
      int j = o & 7, lane = (o >> 3) & 63, rest = o >> 9;
      int hi = lane >> 4, lanelo = lane & 15;
      int k32 = rest % 7, nt = rest / 7;
      int row = k32*32 + hi*8 + j, col = nt*16 + lanelo;
      float v = (row < 112) ? W2r[row*224 + col] : W2s[(row-112)*224 + col];
      W2sw[o] = f2bf(v);
    }
  }
}

// ---------------------------------------------------------------------------
// k_edge: fused edge MLP + alpha. 256 threads (4 waves x 32 edges = 128/tile),
// LDS = h1s only (59.4 KB) -> 2 blocks/CU (2 waves/SIMD). W1/W2 read from
// global pre-swizzled (L1/L2-resident). DPP row-sum epilogue (VALU pipe).
// No barriers inside the tile loop (per-wave-private h1 rows).
// ---------------------------------------------------------------------------
__global__ __launch_bounds__(256, 2) void k_edge(
    const float* __restrict__ rbf, const float* __restrict__ cut,
    const float* __restrict__ ev,
    const int* __restrict__ idx_i, const int* __restrict__ idx_j,
    const unsigned short* __restrict__ W1sw,
    const unsigned short* __restrict__ W2sw,
    const float* __restrict__ b2r, const float* __restrict__ b2s,
    const unsigned short* __restrict__ q_ws, const unsigned short* __restrict__ k_ws,
    float* __restrict__ alpha_ws) {
  __shared__ __bf16 h1s[128*232];    // 59,392 B: 128 edge-rows, +8 elem pad
  int tid = threadIdx.x;
  int wave = tid >> 6, lane = tid & 63;
  int mrow = lane & 15, quad = lane >> 4;
  // Hoisted per-lane constants: layer-2 bias for col = nt*16+mrow (fixed/lane)
  float bias2[14];
  #pragma unroll
  for (int nt = 0; nt < 14; nt++) {
    int colg = nt*16 + mrow;
    bias2[nt] = b2r[colg] + b2s[colg];
  }
  for (int T = blockIdx.x; T < NTILE; T += gridDim.x) {
    int base = T*128 + wave*32;
    // ---- u A-fragments: lane holds edge mrow (per mg), k-chunk quad*8+j ----
    bf16x8 u0[2], u1[2];
    #pragma unroll
    for (int mg = 0; mg < 2; mg++) {
      int e = base + mg*16 + mrow;
      float cu = cut[e];
      const float4* r4 = (const float4*)(rbf + e*32 + quad*8);
      float4 v0 = r4[0], v1 = r4[1];
      u0[mg][0] = (__bf16)(v0.x*cu); u0[mg][1] = (__bf16)(v0.y*cu);
      u0[mg][2] = (__bf16)(v0.z*cu); u0[mg][3] = (__bf16)(v0.w*cu);
      u0[mg][4] = (__bf16)(v1.x*cu); u0[mg][5] = (__bf16)(v1.y*cu);
      u0[mg][6] = (__bf16)(v1.z*cu); u0[mg][7] = (__bf16)(v1.w*cu);
      #pragma unroll
      for (int j = 0; j < 8; j++) u1[mg][j] = (__bf16)0.f;
      if (quad == 0) {   // k = 32..35: l0 contraction + bias row (k=35)
        int ie = idx_i[e], je = idx_j[e];
        const float* evi = ev + ie*NORD; const float* evj = ev + je*NORD;
        float s0 = 0.f, s1 = 0.f, s2 = 0.f;
        #pragma unroll
        for (int o = 0; o < 3; o++)  { float dd = evj[o]-evi[o]; s0 += dd*dd; }
        #pragma unroll
        for (int o = 3; o < 8; o++)  { float dd = evj[o]-evi[o]; s1 += dd*dd; }
        #pragma unroll
        for (int o = 8; o < 15; o++) { float dd = evj[o]-evi[o]; s2 += dd*dd; }
        u1[mg][0] = (__bf16)s0; u1[mg][1] = (__bf16)s1; u1[mg][2] = (__bf16)s2;
        u1[mg][3] = (__bf16)1.0f;   // bias row k=35
      }
    }
    // ---- layer 1: D[edge][feat]; lane holds edges quad*4+r, col mrow ----
    #pragma unroll
    for (int nt = 0; nt < 14; nt++) {
      bf16x8 b0 = *(const bf16x8*)(W1sw + ((nt*2 + 0)*64 + lane)*8);
      bf16x8 b1 = *(const bf16x8*)(W1sw + ((nt*2 + 1)*64 + lane)*8);
      int colg = nt*16 + mrow;
      #pragma unroll
      for (int mg = 0; mg < 2; mg++) {
        f32x4 acc = {0.f, 0.f, 0.f, 0.f};
        acc = MFMA_BF16(u0[mg], b0, acc);
        acc = MFMA_BF16(u1[mg], b1, acc);
        int rowb = wave*32 + mg*16 + quad*4;
        #pragma unroll
        for (int r = 0; r < 4; r++)
          h1s[(rowb + r)*232 + colg] = (__bf16)siluf(acc[r]);
      }
    }
    // ---- h1 A-fragments (same-wave RAW through LDS; lgkmcnt orders) ----
    bf16x8 aa[2][7];
    #pragma unroll
    for (int mg = 0; mg < 2; mg++) {
      int rowa = wave*32 + mg*16 + mrow;
      #pragma unroll
      for (int kt = 0; kt < 7; kt++)
        aa[mg][kt] = *(const bf16x8*)&h1s[rowa*232 + kt*32 + quad*8];
    }
    // edge metadata for epilogue rows (C-layout rows = quad*4+r)
    int ii[2][4], jj[2][4]; float cc[2][4];
    #pragma unroll
    for (int mg = 0; mg < 2; mg++)
      #pragma unroll
      for (int r = 0; r < 4; r++) {
        int e = base + mg*16 + quad*4 + r;
        ii[mg][r] = idx_i[e]; jj[mg][r] = idx_j[e]; cc[mg][r] = cut[e];
      }
    // ---- layer 2 + alpha = sum_f(q_i * w * k_j) * cut ----
    #pragma unroll
    for (int h = 0; h < 7; h++) {
      float part0[4] = {0.f,0.f,0.f,0.f}, part1[4] = {0.f,0.f,0.f,0.f};
      #pragma unroll
      for (int t2 = 0; t2 < 2; t2++) {
        int nt = h*2 + t2;
        float bv = bias2[nt];
        f32x4 acc0 = {bv, bv, bv, bv}, acc1 = {bv, bv, bv, bv};
        #pragma unroll
        for (int kt = 0; kt < 7; kt++) {
          bf16x8 bb = *(const bf16x8*)(W2sw + ((nt*7 + kt)*64 + lane)*8);
          acc0 = MFMA_BF16(aa[0][kt], bb, acc0);
          acc1 = MFMA_BF16(aa[1][kt], bb, acc1);
        }
        int colg = nt*16 + mrow;
        #pragma unroll
        for (int r = 0; r < 4; r++) {
          part0[r] += acc0[r] * bf2f(q_ws[ii[0][r]*FDIM + colg]) * bf2f(k_ws[jj[0][r]*FDIM + colg]);
          part1[r] += acc1[r] * bf2f(q_ws[ii[1][r]*FDIM + colg]) * bf2f(k_ws[jj[1][r]*FDIM + colg]);
        }
      }
      #pragma unroll
      for (int r = 0; r < 4; r++) {
        float v0 = row16_sum(part0[r]);
        float v1 = row16_sum(part1[r]);
        if (mrow == 0) {
          alpha_ws[(base + quad*4 + r)*7 + h]      = v0 * cc[0][r];
          alpha_ws[(base + 16 + quad*4 + r)*7 + h] = v1 * cc[1][r];
        }
      }
    }
  }
}

// ---------------------------------------------------------------------------
// k_agg: one wave per node; 4-wide v loads; unrolled x2; zeros for empty segs.
// ---------------------------------------------------------------------------
__global__ __launch_bounds__(256) void k_agg(
    const float* __restrict__ alpha_ws, const unsigned short* __restrict__ v_ws,
    const float* __restrict__ ylm, const int* __restrict__ idx_j,
    const int* __restrict__ rs, float* __restrict__ out) {
  int n = blockIdx.x*4 + (threadIdx.x >> 6);
  if (n >= NNODE) return;
  int lane = threadIdx.x & 63;
  int s = rs[n], e = rs[n+1];
  if (lane < 56) {
    int c = lane*4, h = lane/14;      // 4 cols per lane, same head (56%4==0)
    float ax = 0.f, ay = 0.f, az = 0.f, aw = 0.f;
    int p = s;
    for (; p + 1 < e; p += 2) {
      int j0 = idx_j[p], j1 = idx_j[p+1];
      float a0 = alpha_ws[p*7 + h], a1 = alpha_ws[(p+1)*7 + h];
      ushort4 w0 = *(const ushort4*)(v_ws + j0*FDIM + c);
      ushort4 w1 = *(const ushort4*)(v_ws + j1*FDIM + c);
      ax += a0*bf2f(w0.x) + a1*bf2f(w1.x);
      ay += a0*bf2f(w0.y) + a1*bf2f(w1.y);
      az += a0*bf2f(w0.z) + a1*bf2f(w1.z);
      aw += a0*bf2f(w0.w) + a1*bf2f(w1.w);
    }
    if (p < e) {
      int j0 = idx_j[p];
      float a0 = alpha_ws[p*7 + h];
      ushort4 w0 = *(const ushort4*)(v_ws + j0*FDIM + c);
      ax += a0*bf2f(w0.x); ay += a0*bf2f(w0.y);
      az += a0*bf2f(w0.z); aw += a0*bf2f(w0.w);
    }
    float4 o4 = {ax, ay, az, aw};
    *(float4*)(out + n*FDIM + c) = o4;
  } else {
    int o = lane - 56;                // 0..7 ; second col o+8 (8..14)
    int dg0 = (o < 3) ? 0 : ((o < 8) ? 1 : 2);
    float a0 = 0.f, a1 = 0.f;
    for (int p = s; p < e; p++) {
      const float* ap = alpha_ws + p*7 + 4;
      a0 += ap[dg0] * ylm[p*NORD + o];
      if (o < 7) a1 += ap[2] * ylm[p*NORD + o + 8];
    }
    out[NXOUT + n*NORD + o] = a0;
    if (o < 7) out[NXOUT + n*NORD + o + 8] = a1;
  }
}

extern "C" void kernel_launch(void* const* d_in, const int* in_sizes, int n_in,
                              void* d_out, int out_size, void* d_ws, size_t ws_size,
                              hipStream_t stream) {
  const float* x     = (const float*)d_in[0];
  const float* ev    = (const float*)d_in[1];
  const float* rbf   = (const float*)d_in[2];
  const float* ylm   = (const float*)d_in[3];
  const float* cut   = (const float*)d_in[4];
  const int*   idx_i = (const int*)d_in[5];
  const int*   idx_j = (const int*)d_in[6];
  const float* W1r   = (const float*)d_in[7];
  const float* b1r   = (const float*)d_in[8];
  const float* W2r   = (const float*)d_in[9];
  const float* b2r   = (const float*)d_in[10];
  const float* W1s   = (const float*)d_in[11];
  const float* b1s   = (const float*)d_in[12];
  const float* W2s   = (const float*)d_in[13];
  const float* b2s   = (const float*)d_in[14];
  const float* Wq    = (const float*)d_in[15];
  const float* Wk    = (const float*)d_in[16];
  const float* Wv    = (const float*)d_in[17];
  float* out = (float*)d_out;
  char* ws = (char*)d_ws;
  unsigned short* q_ws  = (unsigned short*)(ws + 0);          // 11.2 MB
  unsigned short* k_ws  = (unsigned short*)(ws + 11200000);   // 11.2 MB
  unsigned short* v_ws  = (unsigned short*)(ws + 22400000);   // 11.2 MB
  float* alpha_ws       = (float*)(ws + 33600000);            // 11.2 MB
  int* rs               = (int*)(ws + 44800000);              // 100,004 B
  unsigned short* W1sw  = (unsigned short*)(ws + 44900016);   // 28,672 B
  unsigned short* W2sw  = (unsigned short*)(ws + 44928688);   // 100,352 B

  k_pre<<<dim3(NBNODE + 1563 + 3), dim3(256), 0, stream>>>(
      x, Wq, Wk, Wv, idx_i, W1r, W1s, b1r, b1s, W2r, W2s,
      q_ws, k_ws, v_ws, rs, W1sw, W2sw);
  k_edge<<<dim3(512), dim3(256), 0, stream>>>(
      rbf, cut, ev, idx_i, idx_j, W1sw, W2sw, b2r, b2s,
      q_ws, k_ws, alpha_ws);
  k_agg<<<dim3(6250), dim3(256), 0, stream>>>(
      alpha_ws, v_ws, ylm, idx_j, rs, out);
}

// Round 4
// 834.142 us; speedup vs baseline: 1.0986x; 1.0103x over previous
//
#include <hip/hip_runtime.h>
#include <hip/hip_bf16.h>

// Problem constants (from reference)
#define NNODE 25000
#define PEDGE 400000
#define FDIM  224      // F = TF = 224; q/k: 7 heads x 32, v: 4 heads x 56
#define NORD  15
#define NXOUT (NNODE*FDIM)
#define NTILE4 1563    // ceil(PEDGE/256)

typedef __bf16 bf16x8 __attribute__((ext_vector_type(8)));
typedef short  s16x8  __attribute__((ext_vector_type(8)));
typedef float  f32x4  __attribute__((ext_vector_type(4)));

// MFMA wrapper: tolerate either v8bf16 or v8i16 builtin signature across ROCm versions.
template <typename V>
__device__ __forceinline__ auto mfma_impl(V a, V b, f32x4 c, int)
    -> decltype(__builtin_amdgcn_mfma_f32_16x16x32_bf16(a, b, c, 0, 0, 0)) {
  return __builtin_amdgcn_mfma_f32_16x16x32_bf16(a, b, c, 0, 0, 0);
}
template <typename V>
__device__ __forceinline__ f32x4 mfma_impl(V a, V b, f32x4 c, long) {
  return __builtin_amdgcn_mfma_f32_16x16x32_bf16(
      __builtin_bit_cast(s16x8, a), __builtin_bit_cast(s16x8, b), c, 0, 0, 0);
}
__device__ __forceinline__ f32x4 MFMA_BF16(bf16x8 a, bf16x8 b, f32x4 c) {
  return mfma_impl(a, b, c, 0);
}

__device__ __forceinline__ float siluf(float x) { return x / (1.0f + __expf(-x)); }
__device__ __forceinline__ unsigned short f2bf(float x) {
  __hip_bfloat16 h = __float2bfloat16(x);
  return __builtin_bit_cast(unsigned short, h);
}
__device__ __forceinline__ float bf2f(unsigned short u) {
  unsigned int v = ((unsigned int)u) << 16;
  return __builtin_bit_cast(float, v);
}

// DPP 16-lane row sum on the VALU pipe (replaces ds_swizzle shuffles).
template <int CTRL>
__device__ __forceinline__ float dpp_radd(float v) {
  int s = __builtin_amdgcn_update_dpp(0, __builtin_bit_cast(int, v), CTRL, 0xf, 0xf, true);
  return v + __builtin_bit_cast(float, s);
}
__device__ __forceinline__ float row16_sum(float v) {
  v = dpp_radd<0xB1>(v);    // quad_perm [1,0,3,2]  (xor 1)
  v = dpp_radd<0x4E>(v);    // quad_perm [2,3,0,1]  (xor 2)
  v = dpp_radd<0x124>(v);   // row_ror:4
  v = dpp_radd<0x128>(v);   // row_ror:8
  return v;                 // all 16 lanes of the row hold the sum
}

// ---------------------------------------------------------------------------
// k_pre: (a) node q,k,v projections, 32 nodes/block, weights in registers;
//        (b) CSR row_start from sorted idx_i;
//        (c) W1cat (64x224 block-diag + bias row 35) -> swizzled bf16 (global)
//        (d) W2cat (224x224) -> swizzled bf16 (global)
// ---------------------------------------------------------------------------
#define NPB 32
#define NBNODE 782   // ceil(25000/32)
__global__ __launch_bounds__(256) void k_pre(
    const float* __restrict__ x, const float* __restrict__ Wq,
    const float* __restrict__ Wk, const float* __restrict__ Wv,
    const int* __restrict__ idx_i,
    const float* __restrict__ W1r, const float* __restrict__ W1s,
    const float* __restrict__ b1r, const float* __restrict__ b1s,
    const float* __restrict__ W2r, const float* __restrict__ W2s,
    unsigned short* __restrict__ q_ws, unsigned short* __restrict__ k_ws,
    unsigned short* __restrict__ v_ws, int* __restrict__ rs,
    unsigned short* __restrict__ W1sw, unsigned short* __restrict__ W2sw) {
  int b = blockIdx.x, t = threadIdx.x;
  if (b < NBNODE) {
    __shared__ float xs[NPB * FDIM];           // 28,672 B
    int n0 = b * NPB;
    int ncnt = NNODE - n0; if (ncnt > NPB) ncnt = NPB;
    const float4* x4 = (const float4*)(x + n0 * FDIM);
    float4* xs4 = (float4*)xs;
    int tot4 = ncnt * (FDIM / 4);
    for (int i = t; i < tot4; i += 256) xs4[i] = x4[i];
    float wq[32], wk[32], wv[56];
    int h = 0, d = 0;
    if (t < FDIM) {
      #pragma unroll
      for (int j = 0; j < 32; j++) { wq[j] = Wq[t*32 + j]; wk[j] = Wk[t*32 + j]; }
      h = t / 56; d = t - h*56;
      #pragma unroll
      for (int j = 0; j < 56; j++) wv[j] = Wv[(h*56 + d)*56 + j];
    }
    __syncthreads();
    if (t < FDIM) {
      int qh = t >> 5;
      for (int m = 0; m < ncnt; m++) {
        const float* xr = xs + m*FDIM;
        const float* xh = xr + (qh << 5);
        float aq = 0.f, ak = 0.f;
        #pragma unroll
        for (int j = 0; j < 32; j++) { aq += wq[j]*xh[j]; ak += wk[j]*xh[j]; }
        int n = n0 + m;
        q_ws[n*FDIM + t] = f2bf(siluf(aq));
        k_ws[n*FDIM + t] = f2bf(siluf(ak));
        const float* xv = xr + h*56;
        float av = 0.f;
        #pragma unroll
        for (int j = 0; j < 56; j++) av += wv[j]*xv[j];
        v_ws[n*FDIM + t] = f2bf(av);   // no silu on v
      }
    }
  } else if (b < NBNODE + 1563) {
    int p = (b - NBNODE)*256 + t;
    if (p < PEDGE) {
      int cur = idx_i[p];
      if (p == 0) { for (int v = 0; v <= cur; v++) rs[v] = 0; }
      else { int prev = idx_i[p-1]; for (int v = prev+1; v <= cur; v++) rs[v] = p; }
      if (p == PEDGE-1) { for (int v = cur+1; v <= NNODE; v++) rs[v] = PEDGE; }
    }
  } else if (b == NBNODE + 1563) {
    // W1cat[row<64][col<224]; row 35 = b1cat (bias folded into GEMM)
    for (int lin = t; lin < 64*224; lin += 256) {
      int row = lin / 224, col = lin - row*224;
      float v = 0.f;
      if (row < 32) { if (col < 112) v = W1r[row*112 + col]; }
      else if (row < 35) { if (col >= 112) v = W1s[(row-32)*112 + (col-112)]; }
      else if (row == 35) v = (col < 112) ? b1r[col] : b1s[col-112];
      int nt = col >> 4, lanelo = col & 15, k = row >> 5, hi = (row >> 3) & 3, j = row & 7;
      W1sw[(((nt*2 + k)*64) + hi*16 + lanelo)*8 + j] = f2bf(v);
    }
  } else {
    // W2cat (224x224) -> swizzled global, output-linear (coalesced writes)
    int half = b - (NBNODE + 1564);      // 0 or 1
    int o0 = half * 25088;
    for (int o = o0 + t; o < o0 + 25088; o += 256) {
      int j = o & 7, lane = (o >> 3) & 63, rest = o >> 9;
      int hi = lane >> 4, lanelo = lane & 15;
      int k32 = rest % 7, nt = rest / 7;
      int row = k32*32 + hi*8 + j, col = nt*16 + lanelo;
      float v = (row < 112) ? W2r[row*224 + col] : W2s[(row-112)*224 + col];
      W2sw[o] = f2bf(v);
    }
  }
}

// ---------------------------------------------------------------------------
// k_edge: fused edge MLP + alpha. 512 threads = 8 waves x 32 edges = 256-edge
// tiles; h1s 118.8 KB -> 1 block/CU, 8 waves/CU = 2 waves/SIMD.
// NO VGPR cap (R3's __launch_bounds__(,2) -> 128 VGPR caused ~600 MB of spill
// traffic; this structure wants ~160 VGPR). W1/W2 read from global
// pre-swizzled (L1/L2-resident). DPP row-sum epilogue. No barriers in the
// tile loop (per-wave-private h1 rows). Tail: clamp e to PEDGE-1 (benign
// duplicate identical writes).
// ---------------------------------------------------------------------------
__global__ __launch_bounds__(512) void k_edge(
    const float* __restrict__ rbf, const float* __restrict__ cut,
    const float* __restrict__ ev,
    const int* __restrict__ idx_i, const int* __restrict__ idx_j,
    const unsigned short* __restrict__ W1sw,
    const unsigned short* __restrict__ W2sw,
    const float* __restrict__ b2r, const float* __restrict__ b2s,
    const unsigned short* __restrict__ q_ws, const unsigned short* __restrict__ k_ws,
    float* __restrict__ alpha_ws) {
  __shared__ __bf16 h1s[256*232];    // 118,784 B: 256 edge-rows, +8 elem pad
  int tid = threadIdx.x;
  int wave = tid >> 6, lane = tid & 63;
  int mrow = lane & 15, quad = lane >> 4;
  // Hoisted per-lane constants: layer-2 bias for col = nt*16+mrow (fixed/lane)
  float bias2[14];
  #pragma unroll
  for (int nt = 0; nt < 14; nt++) {
    int colg = nt*16 + mrow;
    bias2[nt] = b2r[colg] + b2s[colg];
  }
  for (int T = blockIdx.x; T < NTILE4; T += gridDim.x) {
    int base = T*256 + wave*32;
    // ---- u A-fragments: lane holds edge mrow (per mg), k-chunk quad*8+j ----
    bf16x8 u0[2], u1[2];
    #pragma unroll
    for (int mg = 0; mg < 2; mg++) {
      int e = base + mg*16 + mrow; if (e > PEDGE-1) e = PEDGE-1;
      float cu = cut[e];
      const float4* r4 = (const float4*)(rbf + e*32 + quad*8);
      float4 v0 = r4[0], v1 = r4[1];
      u0[mg][0] = (__bf16)(v0.x*cu); u0[mg][1] = (__bf16)(v0.y*cu);
      u0[mg][2] = (__bf16)(v0.z*cu); u0[mg][3] = (__bf16)(v0.w*cu);
      u0[mg][4] = (__bf16)(v1.x*cu); u0[mg][5] = (__bf16)(v1.y*cu);
      u0[mg][6] = (__bf16)(v1.z*cu); u0[mg][7] = (__bf16)(v1.w*cu);
      #pragma unroll
      for (int j = 0; j < 8; j++) u1[mg][j] = (__bf16)0.f;
      if (quad == 0) {   // k = 32..35: l0 contraction + bias row (k=35)
        int ie = idx_i[e], je = idx_j[e];
        const float* evi = ev + ie*NORD; const float* evj = ev + je*NORD;
        float s0 = 0.f, s1 = 0.f, s2 = 0.f;
        #pragma unroll
        for (int o = 0; o < 3; o++)  { float dd = evj[o]-evi[o]; s0 += dd*dd; }
        #pragma unroll
        for (int o = 3; o < 8; o++)  { float dd = evj[o]-evi[o]; s1 += dd*dd; }
        #pragma unroll
        for (int o = 8; o < 15; o++) { float dd = evj[o]-evi[o]; s2 += dd*dd; }
        u1[mg][0] = (__bf16)s0; u1[mg][1] = (__bf16)s1; u1[mg][2] = (__bf16)s2;
        u1[mg][3] = (__bf16)1.0f;   // bias row k=35
      }
    }
    // ---- layer 1: D[edge][feat]; lane holds edges quad*4+r, col mrow ----
    #pragma unroll
    for (int nt = 0; nt < 14; nt++) {
      bf16x8 b0 = *(const bf16x8*)(W1sw + ((nt*2 + 0)*64 + lane)*8);
      bf16x8 b1 = *(const bf16x8*)(W1sw + ((nt*2 + 1)*64 + lane)*8);
      int colg = nt*16 + mrow;
      #pragma unroll
      for (int mg = 0; mg < 2; mg++) {
        f32x4 acc = {0.f, 0.f, 0.f, 0.f};
        acc = MFMA_BF16(u0[mg], b0, acc);
        acc = MFMA_BF16(u1[mg], b1, acc);
        int rowb = wave*32 + mg*16 + quad*4;
        #pragma unroll
        for (int r = 0; r < 4; r++)
          h1s[(rowb + r)*232 + colg] = (__bf16)siluf(acc[r]);
      }
    }
    // ---- h1 A-fragments (same-wave RAW through LDS; lgkmcnt orders) ----
    bf16x8 aa[2][7];
    #pragma unroll
    for (int mg = 0; mg < 2; mg++) {
      int rowa = wave*32 + mg*16 + mrow;
      #pragma unroll
      for (int kt = 0; kt < 7; kt++)
        aa[mg][kt] = *(const bf16x8*)&h1s[rowa*232 + kt*32 + quad*8];
    }
    // edge metadata for epilogue rows (C-layout rows = quad*4+r)
    int ii[2][4], jj[2][4]; float cc[2][4];
    #pragma unroll
    for (int mg = 0; mg < 2; mg++)
      #pragma unroll
      for (int r = 0; r < 4; r++) {
        int e = base + mg*16 + quad*4 + r; if (e > PEDGE-1) e = PEDGE-1;
        ii[mg][r] = idx_i[e]; jj[mg][r] = idx_j[e]; cc[mg][r] = cut[e];
      }
    // ---- layer 2 + alpha = sum_f(q_i * w * k_j) * cut ----
    #pragma unroll
    for (int h = 0; h < 7; h++) {
      float part0[4] = {0.f,0.f,0.f,0.f}, part1[4] = {0.f,0.f,0.f,0.f};
      #pragma unroll
      for (int t2 = 0; t2 < 2; t2++) {
        int nt = h*2 + t2;
        float bv = bias2[nt];
        f32x4 acc0 = {bv, bv, bv, bv}, acc1 = {bv, bv, bv, bv};
        #pragma unroll
        for (int kt = 0; kt < 7; kt++) {
          bf16x8 bb = *(const bf16x8*)(W2sw + ((nt*7 + kt)*64 + lane)*8);
          acc0 = MFMA_BF16(aa[0][kt], bb, acc0);
          acc1 = MFMA_BF16(aa[1][kt], bb, acc1);
        }
        int colg = nt*16 + mrow;
        #pragma unroll
        for (int r = 0; r < 4; r++) {
          part0[r] += acc0[r] * bf2f(q_ws[ii[0][r]*FDIM + colg]) * bf2f(k_ws[jj[0][r]*FDIM + colg]);
          part1[r] += acc1[r] * bf2f(q_ws[ii[1][r]*FDIM + colg]) * bf2f(k_ws[jj[1][r]*FDIM + colg]);
        }
      }
      #pragma unroll
      for (int r = 0; r < 4; r++) {
        float v0 = row16_sum(part0[r]);
        float v1 = row16_sum(part1[r]);
        if (mrow == 0) {
          int e0 = base + quad*4 + r;      if (e0 > PEDGE-1) e0 = PEDGE-1;
          int e1 = base + 16 + quad*4 + r; if (e1 > PEDGE-1) e1 = PEDGE-1;
          alpha_ws[e0*7 + h] = v0 * cc[0][r];
          alpha_ws[e1*7 + h] = v1 * cc[1][r];
        }
      }
    }
  }
}

// ---------------------------------------------------------------------------
// k_agg: one wave per node; 4-wide v loads; unrolled x2; zeros for empty segs.
// ---------------------------------------------------------------------------
__global__ __launch_bounds__(256) void k_agg(
    const float* __restrict__ alpha_ws, const unsigned short* __restrict__ v_ws,
    const float* __restrict__ ylm, const int* __restrict__ idx_j,
    const int* __restrict__ rs, float* __restrict__ out) {
  int n = blockIdx.x*4 + (threadIdx.x >> 6);
  if (n >= NNODE) return;
  int lane = threadIdx.x & 63;
  int s = rs[n], e = rs[n+1];
  if (lane < 56) {
    int c = lane*4, h = lane/14;      // 4 cols per lane, same head (56%4==0)
    float ax = 0.f, ay = 0.f, az = 0.f, aw = 0.f;
    int p = s;
    for (; p + 1 < e; p += 2) {
      int j0 = idx_j[p], j1 = idx_j[p+1];
      float a0 = alpha_ws[p*7 + h], a1 = alpha_ws[(p+1)*7 + h];
      ushort4 w0 = *(const ushort4*)(v_ws + j0*FDIM + c);
      ushort4 w1 = *(const ushort4*)(v_ws + j1*FDIM + c);
      ax += a0*bf2f(w0.x) + a1*bf2f(w1.x);
      ay += a0*bf2f(w0.y) + a1*bf2f(w1.y);
      az += a0*bf2f(w0.z) + a1*bf2f(w1.z);
      aw += a0*bf2f(w0.w) + a1*bf2f(w1.w);
    }
    if (p < e) {
      int j0 = idx_j[p];
      float a0 = alpha_ws[p*7 + h];
      ushort4 w0 = *(const ushort4*)(v_ws + j0*FDIM + c);
      ax += a0*bf2f(w0.x); ay += a0*bf2f(w0.y);
      az += a0*bf2f(w0.z); aw += a0*bf2f(w0.w);
    }
    float4 o4 = {ax, ay, az, aw};
    *(float4*)(out + n*FDIM + c) = o4;
  } else {
    int o = lane - 56;                // 0..7 ; second col o+8 (8..14)
    int dg0 = (o < 3) ? 0 : ((o < 8) ? 1 : 2);
    float a0 = 0.f, a1 = 0.f;
    for (int p = s; p < e; p++) {
      const float* ap = alpha_ws + p*7 + 4;
      a0 += ap[dg0] * ylm[p*NORD + o];
      if (o < 7) a1 += ap[2] * ylm[p*NORD + o + 8];
    }
    out[NXOUT + n*NORD + o] = a0;
    if (o < 7) out[NXOUT + n*NORD + o + 8] = a1;
  }
}

extern "C" void kernel_launch(void* const* d_in, const int* in_sizes, int n_in,
                              void* d_out, int out_size, void* d_ws, size_t ws_size,
                              hipStream_t stream) {
  const float* x     = (const float*)d_in[0];
  const float* ev    = (const float*)d_in[1];
  const float* rbf   = (const float*)d_in[2];
  const float* ylm   = (const float*)d_in[3];
  const float* cut   = (const float*)d_in[4];
  const int*   idx_i = (const int*)d_in[5];
  const int*   idx_j = (const int*)d_in[6];
  const float* W1r   = (const float*)d_in[7];
  const float* b1r   = (const float*)d_in[8];
  const float* W2r   = (const float*)d_in[9];
  const float* b2r   = (const float*)d_in[10];
  const float* W1s   = (const float*)d_in[11];
  const float* b1s   = (const float*)d_in[12];
  const float* W2s   = (const float*)d_in[13];
  const float* b2s   = (const float*)d_in[14];
  const float* Wq    = (const float*)d_in[15];
  const float* Wk    = (const float*)d_in[16];
  const float* Wv    = (const float*)d_in[17];
  float* out = (float*)d_out;
  char* ws = (char*)d_ws;
  unsigned short* q_ws  = (unsigned short*)(ws + 0);          // 11.2 MB
  unsigned short* k_ws  = (unsigned short*)(ws + 11200000);   // 11.2 MB
  unsigned short* v_ws  = (unsigned short*)(ws + 22400000);   // 11.2 MB
  float* alpha_ws       = (float*)(ws + 33600000);            // 11.2 MB
  int* rs               = (int*)(ws + 44800000);              // 100,004 B
  unsigned short* W1sw  = (unsigned short*)(ws + 44900016);   // 28,672 B
  unsigned short* W2sw  = (unsigned short*)(ws + 44928688);   // 100,352 B

  k_pre<<<dim3(NBNODE + 1563 + 3), dim3(256), 0, stream>>>(
      x, Wq, Wk, Wv, idx_i, W1r, W1s, b1r, b1s, W2r, W2s,
      q_ws, k_ws, v_ws, rs, W1sw, W2sw);
  k_edge<<<dim3(256), dim3(512), 0, stream>>>(
      rbf, cut, ev, idx_i, idx_j, W1sw, W2sw, b2r, b2s,
      q_ws, k_ws, alpha_ws);
  k_agg<<<dim3(6250), dim3(256), 0, stream>>>(
      alpha_ws, v_ws, ylm, idx_j, rs, out);
}

// Round 5
// 737.359 us; speedup vs baseline: 1.2428x; 1.1313x over previous
//
#include <hip/hip_runtime.h>
#include <hip/hip_bf16.h>

// Problem constants (from reference)
#define NNODE 25000
#define PEDGE 400000
#define FDIM  224      // F = TF = 224; q/k: 7 heads x 32, v: 4 heads x 56
#define NORD  15
#define NXOUT (NNODE*FDIM)
#define NTILE 3125     // PEDGE/128 (exact)

typedef __bf16 bf16x8 __attribute__((ext_vector_type(8)));
typedef short  s16x8  __attribute__((ext_vector_type(8)));
typedef float  f32x4  __attribute__((ext_vector_type(4)));

// MFMA wrapper: tolerate either v8bf16 or v8i16 builtin signature across ROCm versions.
template <typename V>
__device__ __forceinline__ auto mfma_impl(V a, V b, f32x4 c, int)
    -> decltype(__builtin_amdgcn_mfma_f32_16x16x32_bf16(a, b, c, 0, 0, 0)) {
  return __builtin_amdgcn_mfma_f32_16x16x32_bf16(a, b, c, 0, 0, 0);
}
template <typename V>
__device__ __forceinline__ f32x4 mfma_impl(V a, V b, f32x4 c, long) {
  return __builtin_amdgcn_mfma_f32_16x16x32_bf16(
      __builtin_bit_cast(s16x8, a), __builtin_bit_cast(s16x8, b), c, 0, 0, 0);
}
__device__ __forceinline__ f32x4 MFMA_BF16(bf16x8 a, bf16x8 b, f32x4 c) {
  return mfma_impl(a, b, c, 0);
}

__device__ __forceinline__ float siluf(float x) { return x / (1.0f + __expf(-x)); }
__device__ __forceinline__ unsigned short f2bf(float x) {
  __hip_bfloat16 h = __float2bfloat16(x);
  return __builtin_bit_cast(unsigned short, h);
}
__device__ __forceinline__ float bf2f(unsigned short u) {
  unsigned int v = ((unsigned int)u) << 16;
  return __builtin_bit_cast(float, v);
}

// DPP 16-lane row sum on the VALU pipe (replaces ds_swizzle shuffles).
template <int CTRL>
__device__ __forceinline__ float dpp_radd(float v) {
  int s = __builtin_amdgcn_update_dpp(0, __builtin_bit_cast(int, v), CTRL, 0xf, 0xf, true);
  return v + __builtin_bit_cast(float, s);
}
__device__ __forceinline__ float row16_sum(float v) {
  v = dpp_radd<0xB1>(v);    // quad_perm [1,0,3,2]  (xor 1)
  v = dpp_radd<0x4E>(v);    // quad_perm [2,3,0,1]  (xor 2)
  v = dpp_radd<0x124>(v);   // row_ror:4
  v = dpp_radd<0x128>(v);   // row_ror:8
  return v;                 // all 16 lanes of the row hold the sum
}

// ---------------------------------------------------------------------------
// k_pre: (a) node q,k,v projections, 32 nodes/block, weights in registers;
//        (b) CSR row_start from sorted idx_i;
//        (c) W1cat (64x224 block-diag + bias row 35) -> swizzled bf16 (global)
//        (d) W2cat (224x224) -> swizzled bf16 (global)
// ---------------------------------------------------------------------------
#define NPB 32
#define NBNODE 782   // ceil(25000/32)
__global__ __launch_bounds__(256) void k_pre(
    const float* __restrict__ x, const float* __restrict__ Wq,
    const float* __restrict__ Wk, const float* __restrict__ Wv,
    const int* __restrict__ idx_i,
    const float* __restrict__ W1r, const float* __restrict__ W1s,
    const float* __restrict__ b1r, const float* __restrict__ b1s,
    const float* __restrict__ W2r, const float* __restrict__ W2s,
    unsigned short* __restrict__ q_ws, unsigned short* __restrict__ k_ws,
    unsigned short* __restrict__ v_ws, int* __restrict__ rs,
    unsigned short* __restrict__ W1sw, unsigned short* __restrict__ W2sw) {
  int b = blockIdx.x, t = threadIdx.x;
  if (b < NBNODE) {
    __shared__ float xs[NPB * FDIM];           // 28,672 B
    int n0 = b * NPB;
    int ncnt = NNODE - n0; if (ncnt > NPB) ncnt = NPB;
    const float4* x4 = (const float4*)(x + n0 * FDIM);
    float4* xs4 = (float4*)xs;
    int tot4 = ncnt * (FDIM / 4);
    for (int i = t; i < tot4; i += 256) xs4[i] = x4[i];
    float wq[32], wk[32], wv[56];
    int h = 0, d = 0;
    if (t < FDIM) {
      #pragma unroll
      for (int j = 0; j < 32; j++) { wq[j] = Wq[t*32 + j]; wk[j] = Wk[t*32 + j]; }
      h = t / 56; d = t - h*56;
      #pragma unroll
      for (int j = 0; j < 56; j++) wv[j] = Wv[(h*56 + d)*56 + j];
    }
    __syncthreads();
    if (t < FDIM) {
      int qh = t >> 5;
      for (int m = 0; m < ncnt; m++) {
        const float* xr = xs + m*FDIM;
        const float* xh = xr + (qh << 5);
        float aq = 0.f, ak = 0.f;
        #pragma unroll
        for (int j = 0; j < 32; j++) { aq += wq[j]*xh[j]; ak += wk[j]*xh[j]; }
        int n = n0 + m;
        q_ws[n*FDIM + t] = f2bf(siluf(aq));
        k_ws[n*FDIM + t] = f2bf(siluf(ak));
        const float* xv = xr + h*56;
        float av = 0.f;
        #pragma unroll
        for (int j = 0; j < 56; j++) av += wv[j]*xv[j];
        v_ws[n*FDIM + t] = f2bf(av);   // no silu on v
      }
    }
  } else if (b < NBNODE + 1563) {
    int p = (b - NBNODE)*256 + t;
    if (p < PEDGE) {
      int cur = idx_i[p];
      if (p == 0) { for (int v = 0; v <= cur; v++) rs[v] = 0; }
      else { int prev = idx_i[p-1]; for (int v = prev+1; v <= cur; v++) rs[v] = p; }
      if (p == PEDGE-1) { for (int v = cur+1; v <= NNODE; v++) rs[v] = PEDGE; }
    }
  } else if (b == NBNODE + 1563) {
    // W1cat[row<64][col<224]; row 35 = b1cat (bias folded into GEMM)
    for (int lin = t; lin < 64*224; lin += 256) {
      int row = lin / 224, col = lin - row*224;
      float v = 0.f;
      if (row < 32) { if (col < 112) v = W1r[row*112 + col]; }
      else if (row < 35) { if (col >= 112) v = W1s[(row-32)*112 + (col-112)]; }
      else if (row == 35) v = (col < 112) ? b1r[col] : b1s[col-112];
      int nt = col >> 4, lanelo = col & 15, k = row >> 5, hi = (row >> 3) & 3, j = row & 7;
      W1sw[(((nt*2 + k)*64) + hi*16 + lanelo)*8 + j] = f2bf(v);
    }
  } else {
    // W2cat (224x224) -> swizzled global, output-linear (coalesced writes)
    int half = b - (NBNODE + 1564);      // 0 or 1
    int o0 = half * 25088;
    for (int o = o0 + t; o < o0 + 25088; o += 256) {
      int j = o & 7, lane = (o >> 3) & 63, rest = o >> 9;
      int hi = lane >> 4, lanelo = lane & 15;
      int k32 = rest % 7, nt = rest / 7;
      int row = k32*32 + hi*8 + j, col = nt*16 + lanelo;
      float v = (row < 112) ? W2r[row*224 + col] : W2s[(row-112)*224 + col];
      W2sw[o] = f2bf(v);
    }
  }
}

// ---------------------------------------------------------------------------
// k_edge: fused edge MLP + alpha. 256 threads (4 waves x 32 edges = 128/tile),
// LDS = h1s only (59.4 KB). PLAIN __launch_bounds__(256): gfx950's unified
// VGPR/AGPR file means any "2 waves/EU" compile-time budget (512-thread flat
// workgroup or explicit (,2)) splits 128 arch + 128 acc and spills ~600 MB of
// scratch (R2/R3/R4 evidence). Plain bounds -> ~160 arch + ~64 acc = ~224
// total, which still RUNS at 2 waves/EU (2x224 <= 512), and LDS allows 2
// blocks/CU -> 8 waves/CU. W1/W2 read from global pre-swizzled
// (L1/L2-resident). DPP row-sum epilogue. No barriers in the tile loop.
// ---------------------------------------------------------------------------
__global__ __launch_bounds__(256) void k_edge(
    const float* __restrict__ rbf, const float* __restrict__ cut,
    const float* __restrict__ ev,
    const int* __restrict__ idx_i, const int* __restrict__ idx_j,
    const unsigned short* __restrict__ W1sw,
    const unsigned short* __restrict__ W2sw,
    const float* __restrict__ b2r, const float* __restrict__ b2s,
    const unsigned short* __restrict__ q_ws, const unsigned short* __restrict__ k_ws,
    float* __restrict__ alpha_ws) {
  __shared__ __bf16 h1s[128*232];    // 59,392 B: 128 edge-rows, +8 elem pad
  int tid = threadIdx.x;
  int wave = tid >> 6, lane = tid & 63;
  int mrow = lane & 15, quad = lane >> 4;
  for (int T = blockIdx.x; T < NTILE; T += gridDim.x) {
    int base = T*128 + wave*32;
    // ---- u A-fragments: lane holds edge mrow (per mg), k-chunk quad*8+j ----
    bf16x8 u0[2], u1[2];
    #pragma unroll
    for (int mg = 0; mg < 2; mg++) {
      int e = base + mg*16 + mrow;
      float cu = cut[e];
      const float4* r4 = (const float4*)(rbf + e*32 + quad*8);
      float4 v0 = r4[0], v1 = r4[1];
      u0[mg][0] = (__bf16)(v0.x*cu); u0[mg][1] = (__bf16)(v0.y*cu);
      u0[mg][2] = (__bf16)(v0.z*cu); u0[mg][3] = (__bf16)(v0.w*cu);
      u0[mg][4] = (__bf16)(v1.x*cu); u0[mg][5] = (__bf16)(v1.y*cu);
      u0[mg][6] = (__bf16)(v1.z*cu); u0[mg][7] = (__bf16)(v1.w*cu);
      #pragma unroll
      for (int j = 0; j < 8; j++) u1[mg][j] = (__bf16)0.f;
      if (quad == 0) {   // k = 32..35: l0 contraction + bias row (k=35)
        int ie = idx_i[e], je = idx_j[e];
        const float* evi = ev + ie*NORD; const float* evj = ev + je*NORD;
        float s0 = 0.f, s1 = 0.f, s2 = 0.f;
        #pragma unroll
        for (int o = 0; o < 3; o++)  { float dd = evj[o]-evi[o]; s0 += dd*dd; }
        #pragma unroll
        for (int o = 3; o < 8; o++)  { float dd = evj[o]-evi[o]; s1 += dd*dd; }
        #pragma unroll
        for (int o = 8; o < 15; o++) { float dd = evj[o]-evi[o]; s2 += dd*dd; }
        u1[mg][0] = (__bf16)s0; u1[mg][1] = (__bf16)s1; u1[mg][2] = (__bf16)s2;
        u1[mg][3] = (__bf16)1.0f;   // bias row k=35
      }
    }
    // ---- layer 1: D[edge][feat]; lane holds edges quad*4+r, col mrow ----
    #pragma unroll
    for (int nt = 0; nt < 14; nt++) {
      bf16x8 b0 = *(const bf16x8*)(W1sw + ((nt*2 + 0)*64 + lane)*8);
      bf16x8 b1 = *(const bf16x8*)(W1sw + ((nt*2 + 1)*64 + lane)*8);
      int colg = nt*16 + mrow;
      #pragma unroll
      for (int mg = 0; mg < 2; mg++) {
        f32x4 acc = {0.f, 0.f, 0.f, 0.f};
        acc = MFMA_BF16(u0[mg], b0, acc);
        acc = MFMA_BF16(u1[mg], b1, acc);
        int rowb = wave*32 + mg*16 + quad*4;
        #pragma unroll
        for (int r = 0; r < 4; r++)
          h1s[(rowb + r)*232 + colg] = (__bf16)siluf(acc[r]);
      }
    }
    // ---- h1 A-fragments (same-wave RAW through LDS; lgkmcnt orders) ----
    bf16x8 aa[2][7];
    #pragma unroll
    for (int mg = 0; mg < 2; mg++) {
      int rowa = wave*32 + mg*16 + mrow;
      #pragma unroll
      for (int kt = 0; kt < 7; kt++)
        aa[mg][kt] = *(const bf16x8*)&h1s[rowa*232 + kt*32 + quad*8];
    }
    // edge metadata for epilogue rows (C-layout rows = quad*4+r)
    int ii[2][4], jj[2][4]; float cc[2][4];
    #pragma unroll
    for (int mg = 0; mg < 2; mg++)
      #pragma unroll
      for (int r = 0; r < 4; r++) {
        int e = base + mg*16 + quad*4 + r;
        ii[mg][r] = idx_i[e]; jj[mg][r] = idx_j[e]; cc[mg][r] = cut[e];
      }
    // ---- layer 2 + alpha = sum_f(q_i * w * k_j) * cut ----
    #pragma unroll
    for (int h = 0; h < 7; h++) {
      float part0[4] = {0.f,0.f,0.f,0.f}, part1[4] = {0.f,0.f,0.f,0.f};
      #pragma unroll
      for (int t2 = 0; t2 < 2; t2++) {
        int nt = h*2 + t2;
        int colg = nt*16 + mrow;
        float bv = b2r[colg] + b2s[colg];   // L1-resident; per-use (reg diet)
        f32x4 acc0 = {bv, bv, bv, bv}, acc1 = {bv, bv, bv, bv};
        #pragma unroll
        for (int kt = 0; kt < 7; kt++) {
          bf16x8 bb = *(const bf16x8*)(W2sw + ((nt*7 + kt)*64 + lane)*8);
          acc0 = MFMA_BF16(aa[0][kt], bb, acc0);
          acc1 = MFMA_BF16(aa[1][kt], bb, acc1);
        }
        #pragma unroll
        for (int r = 0; r < 4; r++) {
          part0[r] += acc0[r] * bf2f(q_ws[ii[0][r]*FDIM + colg]) * bf2f(k_ws[jj[0][r]*FDIM + colg]);
          part1[r] += acc1[r] * bf2f(q_ws[ii[1][r]*FDIM + colg]) * bf2f(k_ws[jj[1][r]*FDIM + colg]);
        }
      }
      #pragma unroll
      for (int r = 0; r < 4; r++) {
        float v0 = row16_sum(part0[r]);
        float v1 = row16_sum(part1[r]);
        if (mrow == 0) {
          alpha_ws[(base + quad*4 + r)*7 + h]      = v0 * cc[0][r];
          alpha_ws[(base + 16 + quad*4 + r)*7 + h] = v1 * cc[1][r];
        }
      }
    }
  }
}

// ---------------------------------------------------------------------------
// k_agg: one wave per node; 4-wide v loads; unrolled x2; zeros for empty segs.
// ---------------------------------------------------------------------------
__global__ __launch_bounds__(256) void k_agg(
    const float* __restrict__ alpha_ws, const unsigned short* __restrict__ v_ws,
    const float* __restrict__ ylm, const int* __restrict__ idx_j,
    const int* __restrict__ rs, float* __restrict__ out) {
  int n = blockIdx.x*4 + (threadIdx.x >> 6);
  if (n >= NNODE) return;
  int lane = threadIdx.x & 63;
  int s = rs[n], e = rs[n+1];
  if (lane < 56) {
    int c = lane*4, h = lane/14;      // 4 cols per lane, same head (56%4==0)
    float ax = 0.f, ay = 0.f, az = 0.f, aw = 0.f;
    int p = s;
    for (; p + 1 < e; p += 2) {
      int j0 = idx_j[p], j1 = idx_j[p+1];
      float a0 = alpha_ws[p*7 + h], a1 = alpha_ws[(p+1)*7 + h];
      ushort4 w0 = *(const ushort4*)(v_ws + j0*FDIM + c);
      ushort4 w1 = *(const ushort4*)(v_ws + j1*FDIM + c);
      ax += a0*bf2f(w0.x) + a1*bf2f(w1.x);
      ay += a0*bf2f(w0.y) + a1*bf2f(w1.y);
      az += a0*bf2f(w0.z) + a1*bf2f(w1.z);
      aw += a0*bf2f(w0.w) + a1*bf2f(w1.w);
    }
    if (p < e) {
      int j0 = idx_j[p];
      float a0 = alpha_ws[p*7 + h];
      ushort4 w0 = *(const ushort4*)(v_ws + j0*FDIM + c);
      ax += a0*bf2f(w0.x); ay += a0*bf2f(w0.y);
      az += a0*bf2f(w0.z); aw += a0*bf2f(w0.w);
    }
    float4 o4 = {ax, ay, az, aw};
    *(float4*)(out + n*FDIM + c) = o4;
  } else {
    int o = lane - 56;                // 0..7 ; second col o+8 (8..14)
    int dg0 = (o < 3) ? 0 : ((o < 8) ? 1 : 2);
    float a0 = 0.f, a1 = 0.f;
    for (int p = s; p < e; p++) {
      const float* ap = alpha_ws + p*7 + 4;
      a0 += ap[dg0] * ylm[p*NORD + o];
      if (o < 7) a1 += ap[2] * ylm[p*NORD + o + 8];
    }
    out[NXOUT + n*NORD + o] = a0;
    if (o < 7) out[NXOUT + n*NORD + o + 8] = a1;
  }
}

extern "C" void kernel_launch(void* const* d_in, const int* in_sizes, int n_in,
                              void* d_out, int out_size, void* d_ws, size_t ws_size,
                              hipStream_t stream) {
  const float* x     = (const float*)d_in[0];
  const float* ev    = (const float*)d_in[1];
  const float* rbf   = (const float*)d_in[2];
  const float* ylm   = (const float*)d_in[3];
  const float* cut   = (const float*)d_in[4];
  const int*   idx_i = (const int*)d_in[5];
  const int*   idx_j = (const int*)d_in[6];
  const float* W1r   = (const float*)d_in[7];
  const float* b1r   = (const float*)d_in[8];
  const float* W2r   = (const float*)d_in[9];
  const float* b2r   = (const float*)d_in[10];
  const float* W1s   = (const float*)d_in[11];
  const float* b1s   = (const float*)d_in[12];
  const float* W2s   = (const float*)d_in[13];
  const float* b2s   = (const float*)d_in[14];
  const float* Wq    = (const float*)d_in[15];
  const float* Wk    = (const float*)d_in[16];
  const float* Wv    = (const float*)d_in[17];
  float* out = (float*)d_out;
  char* ws = (char*)d_ws;
  unsigned short* q_ws  = (unsigned short*)(ws + 0);          // 11.2 MB
  unsigned short* k_ws  = (unsigned short*)(ws + 11200000);   // 11.2 MB
  unsigned short* v_ws  = (unsigned short*)(ws + 22400000);   // 11.2 MB
  float* alpha_ws       = (float*)(ws + 33600000);            // 11.2 MB
  int* rs               = (int*)(ws + 44800000);              // 100,004 B
  unsigned short* W1sw  = (unsigned short*)(ws + 44900016);   // 28,672 B
  unsigned short* W2sw  = (unsigned short*)(ws + 44928688);   // 100,352 B

  k_pre<<<dim3(NBNODE + 1563 + 3), dim3(256), 0, stream>>>(
      x, Wq, Wk, Wv, idx_i, W1r, W1s, b1r, b1s, W2r, W2s,
      q_ws, k_ws, v_ws, rs, W1sw, W2sw);
  k_edge<<<dim3(512), dim3(256), 0, stream>>>(
      rbf, cut, ev, idx_i, idx_j, W1sw, W2sw, b2r, b2s,
      q_ws, k_ws, alpha_ws);
  k_agg<<<dim3(6250), dim3(256), 0, stream>>>(
      alpha_ws, v_ws, ylm, idx_j, rs, out);
}

// Round 6
// 595.762 us; speedup vs baseline: 1.5381x; 1.2377x over previous
//
#include <hip/hip_runtime.h>
#include <hip/hip_bf16.h>

// Problem constants (from reference)
#define NNODE 25000
#define PEDGE 400000
#define FDIM  224      // F = TF = 224; q/k: 7 heads x 32, v: 4 heads x 56
#define NORD  15
#define NXOUT (NNODE*FDIM)
#define NTILE 3125     // PEDGE/128 (exact)

typedef __bf16 bf16x8 __attribute__((ext_vector_type(8)));
typedef short  s16x8  __attribute__((ext_vector_type(8)));
typedef float  f32x4  __attribute__((ext_vector_type(4)));

// MFMA wrapper: tolerate either v8bf16 or v8i16 builtin signature across ROCm versions.
template <typename V>
__device__ __forceinline__ auto mfma_impl(V a, V b, f32x4 c, int)
    -> decltype(__builtin_amdgcn_mfma_f32_16x16x32_bf16(a, b, c, 0, 0, 0)) {
  return __builtin_amdgcn_mfma_f32_16x16x32_bf16(a, b, c, 0, 0, 0);
}
template <typename V>
__device__ __forceinline__ f32x4 mfma_impl(V a, V b, f32x4 c, long) {
  return __builtin_amdgcn_mfma_f32_16x16x32_bf16(
      __builtin_bit_cast(s16x8, a), __builtin_bit_cast(s16x8, b), c, 0, 0, 0);
}
__device__ __forceinline__ f32x4 MFMA_BF16(bf16x8 a, bf16x8 b, f32x4 c) {
  return mfma_impl(a, b, c, 0);
}

__device__ __forceinline__ float siluf(float x) { return x / (1.0f + __expf(-x)); }
__device__ __forceinline__ unsigned short f2bf(float x) {
  __hip_bfloat16 h = __float2bfloat16(x);
  return __builtin_bit_cast(unsigned short, h);
}
__device__ __forceinline__ float bf2f(unsigned short u) {
  unsigned int v = ((unsigned int)u) << 16;
  return __builtin_bit_cast(float, v);
}

// DPP 16-lane row sum on the VALU pipe (replaces ds_swizzle shuffles).
template <int CTRL>
__device__ __forceinline__ float dpp_radd(float v) {
  int s = __builtin_amdgcn_update_dpp(0, __builtin_bit_cast(int, v), CTRL, 0xf, 0xf, true);
  return v + __builtin_bit_cast(float, s);
}
__device__ __forceinline__ float row16_sum(float v) {
  v = dpp_radd<0xB1>(v);    // quad_perm [1,0,3,2]  (xor 1)
  v = dpp_radd<0x4E>(v);    // quad_perm [2,3,0,1]  (xor 2)
  v = dpp_radd<0x124>(v);   // row_ror:4
  v = dpp_radd<0x128>(v);   // row_ror:8
  return v;                 // all 16 lanes of the row hold the sum
}

// ---------------------------------------------------------------------------
// k_pre: (a) node q,k,v projections, 8 nodes/block, weights in registers;
//        (b) CSR row_start from sorted idx_i;
//        (c) W1cat (64x224 block-diag + bias row 35) -> swizzled bf16 (global)
//        (d) W2cat (224x224) -> swizzled bf16 (global)
// ---------------------------------------------------------------------------
#define NPB 8
#define NBNODE 3125   // 25000/8
__global__ __launch_bounds__(256) void k_pre(
    const float* __restrict__ x, const float* __restrict__ Wq,
    const float* __restrict__ Wk, const float* __restrict__ Wv,
    const int* __restrict__ idx_i,
    const float* __restrict__ W1r, const float* __restrict__ W1s,
    const float* __restrict__ b1r, const float* __restrict__ b1s,
    const float* __restrict__ W2r, const float* __restrict__ W2s,
    unsigned short* __restrict__ q_ws, unsigned short* __restrict__ k_ws,
    unsigned short* __restrict__ v_ws, int* __restrict__ rs,
    unsigned short* __restrict__ W1sw, unsigned short* __restrict__ W2sw) {
  int b = blockIdx.x, t = threadIdx.x;
  if (b < NBNODE) {
    __shared__ float xs[NPB * FDIM];           // 7,168 B
    int n0 = b * NPB;
    const float4* x4 = (const float4*)(x + n0 * FDIM);
    float4* xs4 = (float4*)xs;
    for (int i = t; i < NPB * (FDIM/4); i += 256) xs4[i] = x4[i];
    float wq[32], wk[32], wv[56];
    int h = 0, d = 0;
    if (t < FDIM) {
      #pragma unroll
      for (int j = 0; j < 32; j++) { wq[j] = Wq[t*32 + j]; wk[j] = Wk[t*32 + j]; }
      h = t / 56; d = t - h*56;
      #pragma unroll
      for (int j = 0; j < 56; j++) wv[j] = Wv[(h*56 + d)*56 + j];
    }
    __syncthreads();
    if (t < FDIM) {
      int qh = t >> 5;
      #pragma unroll
      for (int m = 0; m < NPB; m++) {
        const float* xr = xs + m*FDIM;
        const float* xh = xr + (qh << 5);
        float aq = 0.f, ak = 0.f;
        #pragma unroll
        for (int j = 0; j < 32; j++) { aq += wq[j]*xh[j]; ak += wk[j]*xh[j]; }
        int n = n0 + m;
        q_ws[n*FDIM + t] = f2bf(siluf(aq));
        k_ws[n*FDIM + t] = f2bf(siluf(ak));
        const float* xv = xr + h*56;
        float av = 0.f;
        #pragma unroll
        for (int j = 0; j < 56; j++) av += wv[j]*xv[j];
        v_ws[n*FDIM + t] = f2bf(av);   // no silu on v
      }
    }
  } else if (b < NBNODE + 1563) {
    int p = (b - NBNODE)*256 + t;
    if (p < PEDGE) {
      int cur = idx_i[p];
      if (p == 0) { for (int v = 0; v <= cur; v++) rs[v] = 0; }
      else { int prev = idx_i[p-1]; for (int v = prev+1; v <= cur; v++) rs[v] = p; }
      if (p == PEDGE-1) { for (int v = cur+1; v <= NNODE; v++) rs[v] = PEDGE; }
    }
  } else if (b == NBNODE + 1563) {
    // W1cat[row<64][col<224]; row 35 = b1cat (bias folded into GEMM)
    for (int lin = t; lin < 64*224; lin += 256) {
      int row = lin / 224, col = lin - row*224;
      float v = 0.f;
      if (row < 32) { if (col < 112) v = W1r[row*112 + col]; }
      else if (row < 35) { if (col >= 112) v = W1s[(row-32)*112 + (col-112)]; }
      else if (row == 35) v = (col < 112) ? b1r[col] : b1s[col-112];
      int nt = col >> 4, lanelo = col & 15, k = row >> 5, hi = (row >> 3) & 3, j = row & 7;
      W1sw[(((nt*2 + k)*64) + hi*16 + lanelo)*8 + j] = f2bf(v);
    }
  } else {
    // W2cat (224x224) -> swizzled global, output-linear (coalesced writes)
    int half = b - (NBNODE + 1564);      // 0 or 1
    int o0 = half * 25088;
    for (int o = o0 + t; o < o0 + 25088; o += 256) {
      int j = o & 7, lane = (o >> 3) & 63, rest = o >> 9;
      int hi = lane >> 4, lanelo = lane & 15;
      int k32 = rest % 7, nt = rest / 7;
      int row = k32*32 + hi*8 + j, col = nt*16 + lanelo;
      float v = (row < 112) ? W2r[row*224 + col] : W2s[(row-112)*224 + col];
      W2sw[o] = f2bf(v);
    }
  }
}

// ---------------------------------------------------------------------------
// k_edge: fused edge MLP + alpha. 256 threads (4 waves x 32 edges = 128/tile),
// LDS = h1s only (59.4 KB) -> 2 blocks/CU. __launch_bounds__(256,2) pins the
// 256-total-regs/wave budget (2 waves/EU); the epilogue h-loop is
// #pragma unroll 1 so the live-set (aa 56 + one h-iter's 14 bb loads + acc)
// fits that budget WITHOUT scratch spills. R3/R4/R5 evidence: fully-unrolled
// epilogue spills 0.4-0.9 GB of scratch at any allocatable budget.
// W1/W2 read from global pre-swizzled (L2-resident). DPP row-sum epilogue.
// No barriers in the tile loop (per-wave-private h1 rows).
// ---------------------------------------------------------------------------
__global__ __launch_bounds__(256, 2) void k_edge(
    const float* __restrict__ rbf, const float* __restrict__ cut,
    const float* __restrict__ ev,
    const int* __restrict__ idx_i, const int* __restrict__ idx_j,
    const unsigned short* __restrict__ W1sw,
    const unsigned short* __restrict__ W2sw,
    const float* __restrict__ b2r, const float* __restrict__ b2s,
    const unsigned short* __restrict__ q_ws, const unsigned short* __restrict__ k_ws,
    float* __restrict__ alpha_ws) {
  __shared__ __bf16 h1s[128*232];    // 59,392 B: 128 edge-rows, +8 elem pad
  int tid = threadIdx.x;
  int wave = tid >> 6, lane = tid & 63;
  int mrow = lane & 15, quad = lane >> 4;
  for (int T = blockIdx.x; T < NTILE; T += gridDim.x) {
    int base = T*128 + wave*32;
    // ---- u A-fragments: lane holds edge mrow (per mg), k-chunk quad*8+j ----
    bf16x8 u0[2], u1[2];
    #pragma unroll
    for (int mg = 0; mg < 2; mg++) {
      int e = base + mg*16 + mrow;
      float cu = cut[e];
      const float4* r4 = (const float4*)(rbf + e*32 + quad*8);
      float4 v0 = r4[0], v1 = r4[1];
      u0[mg][0] = (__bf16)(v0.x*cu); u0[mg][1] = (__bf16)(v0.y*cu);
      u0[mg][2] = (__bf16)(v0.z*cu); u0[mg][3] = (__bf16)(v0.w*cu);
      u0[mg][4] = (__bf16)(v1.x*cu); u0[mg][5] = (__bf16)(v1.y*cu);
      u0[mg][6] = (__bf16)(v1.z*cu); u0[mg][7] = (__bf16)(v1.w*cu);
      #pragma unroll
      for (int j = 0; j < 8; j++) u1[mg][j] = (__bf16)0.f;
      if (quad == 0) {   // k = 32..35: l0 contraction + bias row (k=35)
        int ie = idx_i[e], je = idx_j[e];
        const float* evi = ev + ie*NORD; const float* evj = ev + je*NORD;
        float s0 = 0.f, s1 = 0.f, s2 = 0.f;
        #pragma unroll
        for (int o = 0; o < 3; o++)  { float dd = evj[o]-evi[o]; s0 += dd*dd; }
        #pragma unroll
        for (int o = 3; o < 8; o++)  { float dd = evj[o]-evi[o]; s1 += dd*dd; }
        #pragma unroll
        for (int o = 8; o < 15; o++) { float dd = evj[o]-evi[o]; s2 += dd*dd; }
        u1[mg][0] = (__bf16)s0; u1[mg][1] = (__bf16)s1; u1[mg][2] = (__bf16)s2;
        u1[mg][3] = (__bf16)1.0f;   // bias row k=35
      }
    }
    // ---- layer 1: D[edge][feat]; lane holds edges quad*4+r, col mrow ----
    #pragma unroll
    for (int nt = 0; nt < 14; nt++) {
      bf16x8 b0 = *(const bf16x8*)(W1sw + ((nt*2 + 0)*64 + lane)*8);
      bf16x8 b1 = *(const bf16x8*)(W1sw + ((nt*2 + 1)*64 + lane)*8);
      int colg = nt*16 + mrow;
      #pragma unroll
      for (int mg = 0; mg < 2; mg++) {
        f32x4 acc = {0.f, 0.f, 0.f, 0.f};
        acc = MFMA_BF16(u0[mg], b0, acc);
        acc = MFMA_BF16(u1[mg], b1, acc);
        int rowb = wave*32 + mg*16 + quad*4;
        #pragma unroll
        for (int r = 0; r < 4; r++)
          h1s[(rowb + r)*232 + colg] = (__bf16)siluf(acc[r]);
      }
    }
    // ---- h1 A-fragments (same-wave RAW through LDS; lgkmcnt orders) ----
    bf16x8 aa[2][7];
    #pragma unroll
    for (int mg = 0; mg < 2; mg++) {
      int rowa = wave*32 + mg*16 + mrow;
      #pragma unroll
      for (int kt = 0; kt < 7; kt++)
        aa[mg][kt] = *(const bf16x8*)&h1s[rowa*232 + kt*32 + quad*8];
    }
    // edge metadata for epilogue rows (C-layout rows = quad*4+r)
    int ii[2][4], jj[2][4]; float cc[2][4];
    #pragma unroll
    for (int mg = 0; mg < 2; mg++)
      #pragma unroll
      for (int r = 0; r < 4; r++) {
        int e = base + mg*16 + quad*4 + r;
        ii[mg][r] = idx_i[e]; jj[mg][r] = idx_j[e]; cc[mg][r] = cut[e];
      }
    // ---- layer 2 + alpha = sum_f(q_i * w * k_j) * cut ----
    // unroll 1: cap the schedulable live-set (one h-iter = 14 bb + 16 gathers)
    #pragma unroll 1
    for (int h = 0; h < 7; h++) {
      float part0[4] = {0.f,0.f,0.f,0.f}, part1[4] = {0.f,0.f,0.f,0.f};
      #pragma unroll
      for (int t2 = 0; t2 < 2; t2++) {
        int nt = h*2 + t2;
        int colg = nt*16 + mrow;
        float bv = b2r[colg] + b2s[colg];   // L1-resident
        f32x4 acc0 = {bv, bv, bv, bv}, acc1 = {bv, bv, bv, bv};
        #pragma unroll
        for (int kt = 0; kt < 7; kt++) {
          bf16x8 bb = *(const bf16x8*)(W2sw + ((nt*7 + kt)*64 + lane)*8);
          acc0 = MFMA_BF16(aa[0][kt], bb, acc0);
          acc1 = MFMA_BF16(aa[1][kt], bb, acc1);
        }
        #pragma unroll
        for (int r = 0; r < 4; r++) {
          part0[r] += acc0[r] * bf2f(q_ws[ii[0][r]*FDIM + colg]) * bf2f(k_ws[jj[0][r]*FDIM + colg]);
          part1[r] += acc1[r] * bf2f(q_ws[ii[1][r]*FDIM + colg]) * bf2f(k_ws[jj[1][r]*FDIM + colg]);
        }
      }
      #pragma unroll
      for (int r = 0; r < 4; r++) {
        float v0 = row16_sum(part0[r]);
        float v1 = row16_sum(part1[r]);
        if (mrow == 0) {
          alpha_ws[(base + quad*4 + r)*7 + h]      = v0 * cc[0][r];
          alpha_ws[(base + 16 + quad*4 + r)*7 + h] = v1 * cc[1][r];
        }
      }
    }
  }
}

// ---------------------------------------------------------------------------
// k_agg: one wave per node; 4-wide v loads; unrolled x2; zeros for empty segs.
// ---------------------------------------------------------------------------
__global__ __launch_bounds__(256) void k_agg(
    const float* __restrict__ alpha_ws, const unsigned short* __restrict__ v_ws,
    const float* __restrict__ ylm, const int* __restrict__ idx_j,
    const int* __restrict__ rs, float* __restrict__ out) {
  int n = blockIdx.x*4 + (threadIdx.x >> 6);
  if (n >= NNODE) return;
  int lane = threadIdx.x & 63;
  int s = rs[n], e = rs[n+1];
  if (lane < 56) {
    int c = lane*4, h = lane/14;      // 4 cols per lane, same head (56%4==0)
    float ax = 0.f, ay = 0.f, az = 0.f, aw = 0.f;
    int p = s;
    for (; p + 1 < e; p += 2) {
      int j0 = idx_j[p], j1 = idx_j[p+1];
      float a0 = alpha_ws[p*7 + h], a1 = alpha_ws[(p+1)*7 + h];
      ushort4 w0 = *(const ushort4*)(v_ws + j0*FDIM + c);
      ushort4 w1 = *(const ushort4*)(v_ws + j1*FDIM + c);
      ax += a0*bf2f(w0.x) + a1*bf2f(w1.x);
      ay += a0*bf2f(w0.y) + a1*bf2f(w1.y);
      az += a0*bf2f(w0.z) + a1*bf2f(w1.z);
      aw += a0*bf2f(w0.w) + a1*bf2f(w1.w);
    }
    if (p < e) {
      int j0 = idx_j[p];
      float a0 = alpha_ws[p*7 + h];
      ushort4 w0 = *(const ushort4*)(v_ws + j0*FDIM + c);
      ax += a0*bf2f(w0.x); ay += a0*bf2f(w0.y);
      az += a0*bf2f(w0.z); aw += a0*bf2f(w0.w);
    }
    float4 o4 = {ax, ay, az, aw};
    *(float4*)(out + n*FDIM + c) = o4;
  } else {
    int o = lane - 56;                // 0..7 ; second col o+8 (8..14)
    int dg0 = (o < 3) ? 0 : ((o < 8) ? 1 : 2);
    float a0 = 0.f, a1 = 0.f;
    for (int p = s; p < e; p++) {
      const float* ap = alpha_ws + p*7 + 4;
      a0 += ap[dg0] * ylm[p*NORD + o];
      if (o < 7) a1 += ap[2] * ylm[p*NORD + o + 8];
    }
    out[NXOUT + n*NORD + o] = a0;
    if (o < 7) out[NXOUT + n*NORD + o + 8] = a1;
  }
}

extern "C" void kernel_launch(void* const* d_in, const int* in_sizes, int n_in,
                              void* d_out, int out_size, void* d_ws, size_t ws_size,
                              hipStream_t stream) {
  const float* x     = (const float*)d_in[0];
  const float* ev    = (const float*)d_in[1];
  const float* rbf   = (const float*)d_in[2];
  const float* ylm   = (const float*)d_in[3];
  const float* cut   = (const float*)d_in[4];
  const int*   idx_i = (const int*)d_in[5];
  const int*   idx_j = (const int*)d_in[6];
  const float* W1r   = (const float*)d_in[7];
  const float* b1r   = (const float*)d_in[8];
  const float* W2r   = (const float*)d_in[9];
  const float* b2r   = (const float*)d_in[10];
  const float* W1s   = (const float*)d_in[11];
  const float* b1s   = (const float*)d_in[12];
  const float* W2s   = (const float*)d_in[13];
  const float* b2s   = (const float*)d_in[14];
  const float* Wq    = (const float*)d_in[15];
  const float* Wk    = (const float*)d_in[16];
  const float* Wv    = (const float*)d_in[17];
  float* out = (float*)d_out;
  char* ws = (char*)d_ws;
  unsigned short* q_ws  = (unsigned short*)(ws + 0);          // 11.2 MB
  unsigned short* k_ws  = (unsigned short*)(ws + 11200000);   // 11.2 MB
  unsigned short* v_ws  = (unsigned short*)(ws + 22400000);   // 11.2 MB
  float* alpha_ws       = (float*)(ws + 33600000);            // 11.2 MB
  int* rs               = (int*)(ws + 44800000);              // 100,004 B
  unsigned short* W1sw  = (unsigned short*)(ws + 44900016);   // 28,672 B
  unsigned short* W2sw  = (unsigned short*)(ws + 44928688);   // 100,352 B

  k_pre<<<dim3(NBNODE + 1563 + 3), dim3(256), 0, stream>>>(
      x, Wq, Wk, Wv, idx_i, W1r, W1s, b1r, b1s, W2r, W2s,
      q_ws, k_ws, v_ws, rs, W1sw, W2sw);
  k_edge<<<dim3(512), dim3(256), 0, stream>>>(
      rbf, cut, ev, idx_i, idx_j, W1sw, W2sw, b2r, b2s,
      q_ws, k_ws, alpha_ws);
  k_agg<<<dim3(6250), dim3(256), 0, stream>>>(
      alpha_ws, v_ws, ylm, idx_j, rs, out);
}